// Round 14
// baseline (125.558 us; speedup 1.0000x reference)
//
#include <hip/hip_runtime.h>
#include <math.h>

#define KNOTS 8
#define HIDN 32
#define TT 4096
#define CC 512
#define NB 32
#define BOUNDF 5.0f
#define CT 32            // channels per block
#define NTG 16           // t-groups (threads striding over T)
#define TPT (TT / NTG)   // 256 elements per thread
#define NPAIR (TPT / 2)  // 128 packed bf16 pairs held in VGPRs
#define CH 16            // gload_lds rounds per staging buffer
#define NBUF (TPT / CH)  // 16 buffers' worth

typedef __attribute__((address_space(3))) void       lds_void;
typedef const __attribute__((address_space(1))) void g_void;

// One block = one (batch, 32-channel) slice, 512 threads = 32 c-lanes x 16 tg.
// P1 (NEW): per-wave double-buffered global_load_lds staging -- load depth is
//   vmcnt-limited (16-32 in flight/wave, zero VGPR cost) instead of VGPR-limited.
//   Each thread consumes ITS OWN LDS slots (no cross-wave deps, no barriers).
//   Moments accumulated in f32; values packed bf16x2 into registers (R10 hold).
// P2: unchanged from R10 (121.2us baseline): unpack regs -> binary bin search ->
//   float2 LDS tables (0-conflict) -> spline -> NT store.
__global__ __launch_bounds__(512, 2)
void k_fused(const float* __restrict__ x, const float* __restrict__ W1,
             const float* __restrict__ b1, const float* __restrict__ W2,
             const float* __restrict__ b2, float* __restrict__ out)
{
    const int bb = blockIdx.y;               // 0..31
    const int c0 = blockIdx.x * CT;          // 0,32,...,480
    const int ci = threadIdx.x & (CT - 1);   // 0..31
    const int tg = threadIdx.x >> 5;         // 0..15
    const int w  = threadIdx.x >> 6;         // wave 0..7
    const int ln = threadIdx.x & 63;         // lane

    __shared__ float stage[2][8][CH * 64];   // 64 KB staging (per-wave regions)
    __shared__ float red[NTG][4][CT];
    __shared__ float mom[4][CT];
    __shared__ float pA[CT], pB[CT];
    __shared__ float pKx[7][CT];
    __shared__ float2 bZ[KNOTS][CT];   // (-kxl*invw, invw)
    __shared__ float2 bY[KNOTS][CT];   // (kyl, h)
    __shared__ float2 bD[KNOTS][CT];   // (d0, d0+d1)

    const size_t base = (size_t)bb * TT * CC + c0 + ci;
    const float* pxt = x + base + (size_t)tg * CC;

    // ---- Phase 1: staged read (DMA->LDS), exact moments, pack to bf16 regs ----
    unsigned int xp[NPAIR];
    float s1 = 0.f, s2 = 0.f, s3 = 0.f, s4 = 0.f;

#define ISSUE(BUF, KBASE)                                                        \
    {                                                                            \
        float* dst_ = &stage[(BUF)][w][0];                                       \
        _Pragma("unroll")                                                        \
        for (int r_ = 0; r_ < CH; ++r_)                                          \
            __builtin_amdgcn_global_load_lds(                                    \
                (g_void*)(pxt + (size_t)((KBASE) + r_) * (NTG * CC)),            \
                (lds_void*)(dst_ + r_ * 64), 4, 0, 0);                           \
    }

    ISSUE(0, 0);
    #pragma unroll
    for (int blk = 0; blk < NBUF; ++blk) {
        if (blk + 1 < NBUF) {
            asm volatile("s_waitcnt lgkmcnt(0)" ::: "memory"); // target buf reads done
            ISSUE((blk + 1) & 1, (blk + 1) * CH);
            asm volatile("s_waitcnt vmcnt(16)" ::: "memory");  // prev buf landed
        } else {
            asm volatile("s_waitcnt vmcnt(0)" ::: "memory");
        }
        const float* src = &stage[blk & 1][w][0];
        #pragma unroll
        for (int p = 0; p < CH / 2; ++p) {
            const float v0 = src[(2 * p)     * 64 + ln];
            const float v1 = src[(2 * p + 1) * 64 + ln];
            const float v0sq = v0 * v0, v1sq = v1 * v1;
            s1 += v0;                    s1 += v1;
            s2 = fmaf(v0,   v0,   s2);   s2 = fmaf(v1,   v1,   s2);
            s3 = fmaf(v0sq, v0,   s3);   s3 = fmaf(v1sq, v1,   s3);
            s4 = fmaf(v0sq, v0sq, s4);   s4 = fmaf(v1sq, v1sq, s4);
            unsigned int pk;
            asm("v_cvt_pk_bf16_f32 %0, %1, %2" : "=v"(pk) : "v"(v0), "v"(v1));
            xp[blk * (CH / 2) + p] = pk;
        }
    }
#undef ISSUE

    red[tg][0][ci] = s1; red[tg][1][ci] = s2;
    red[tg][2][ci] = s3; red[tg][3][ci] = s4;
    __syncthreads();

    if (threadIdx.x < 4 * CT) {
        const int m = threadIdx.x >> 5, c = threadIdx.x & (CT - 1);
        float acc = 0.f;
        #pragma unroll
        for (int g = 0; g < NTG; ++g) acc += red[g][m][c];
        mom[m][c] = acc;
    }
    __syncthreads();

    // ---- Finalize: one lane per channel row ----
    if (threadIdx.x < CT) {
        const int c = threadIdx.x;
        const float n  = (float)TT;
        const float t1 = mom[0][c], t2 = mom[1][c], t3 = mom[2][c], t4 = mom[3][c];
        const float mu  = t1 / n;
        const float ex2 = t2 / n, ex3 = t3 / n, ex4 = t4 / n;
        float var = (t2 - n * mu * mu) / (n - 1.f);
        var = fmaxf(var, 0.f);
        const float sig  = fmaxf(sqrtf(var), 1e-4f);
        const float inv  = 1.f / sig;
        const float mu2  = mu * mu;
        const float ez3  = ex3 - 3.f * mu * ex2 + 2.f * mu * mu2;
        const float ez4  = ex4 - 4.f * mu * ex3 + 6.f * mu2 * ex2 - 3.f * mu2 * mu2;
        const float inv2 = inv * inv;
        const float skew  = ez3 * inv2 * inv;
        const float ekurt = ez4 * inv2 * inv2 - 3.f;

        float hid[HIDN];
        #pragma unroll
        for (int h = 0; h < HIDN; ++h) {
            float v = fmaf(W1[2*h], skew, fmaf(W1[2*h+1], ekurt, b1[h]));
            hid[h] = fmaxf(v, 0.f);
        }

        float e[KNOTS], kxr[KNOTS+1], kyr[KNOTS+1], dr[KNOTS+1];
        {   // widths -> kx
            float mx = -1e30f;
            #pragma unroll
            for (int o = 0; o < KNOTS; ++o) {
                float acc = b2[o];
                #pragma unroll
                for (int h = 0; h < HIDN; ++h) acc = fmaf(W2[o*HIDN + h], hid[h], acc);
                e[o] = acc; mx = fmaxf(mx, acc);
            }
            float sum = 0.f;
            #pragma unroll
            for (int o = 0; o < KNOTS; ++o) { e[o] = expf(e[o] - mx); sum += e[o]; }
            const float scale = (2.f * BOUNDF) / sum;
            float cum = -BOUNDF; kxr[0] = -BOUNDF;
            #pragma unroll
            for (int o = 0; o < KNOTS; ++o) { cum = fmaf(e[o], scale, cum); kxr[o+1] = cum; }
        }
        {   // heights -> ky
            float mx = -1e30f;
            #pragma unroll
            for (int o = 0; o < KNOTS; ++o) {
                float acc = b2[KNOTS + o];
                #pragma unroll
                for (int h = 0; h < HIDN; ++h) acc = fmaf(W2[(KNOTS+o)*HIDN + h], hid[h], acc);
                e[o] = acc; mx = fmaxf(mx, acc);
            }
            float sum = 0.f;
            #pragma unroll
            for (int o = 0; o < KNOTS; ++o) { e[o] = expf(e[o] - mx); sum += e[o]; }
            const float scale = (2.f * BOUNDF) / sum;
            float cum = -BOUNDF; kyr[0] = -BOUNDF;
            #pragma unroll
            for (int o = 0; o < KNOTS; ++o) { cum = fmaf(e[o], scale, cum); kyr[o+1] = cum; }
        }
        #pragma unroll
        for (int o = 0; o < KNOTS+1; ++o) {  // derivs = softplus + 1e-3
            float acc = b2[2*KNOTS + o];
            #pragma unroll
            for (int h = 0; h < HIDN; ++h) acc = fmaf(W2[(2*KNOTS+o)*HIDN + h], hid[h], acc);
            float sp = fmaxf(acc, 0.f) + log1pf(expf(-fabsf(acc)));
            dr[o] = sp + 1e-3f;
        }

        pA[c] = inv;
        pB[c] = -mu * inv;
        #pragma unroll
        for (int j = 1; j <= 7; ++j) pKx[j-1][c] = kxr[j];
        #pragma unroll
        for (int j = 0; j < KNOTS; ++j) {
            const float w_    = kxr[j+1] - kxr[j];
            const float wm   = fmaxf(w_, 1e-8f);
            const float invw = 1.f / wm;
            const float h    = kyr[j+1] - kyr[j];
            bZ[j][c] = make_float2(-kxr[j] * invw, invw);
            bY[j][c] = make_float2(kyr[j], h);
            bD[j][c] = make_float2(dr[j], dr[j] + dr[j+1]);
        }
    }
    __syncthreads();

    // ---- Phase 2: unpack from registers, apply spline, NT store ----
    const float a  = pA[ci];
    const float bz = pB[ci];
    const float kx1 = pKx[0][ci], kx2 = pKx[1][ci], kx3 = pKx[2][ci],
                kx4 = pKx[3][ci], kx5 = pKx[4][ci], kx6 = pKx[5][ci],
                kx7 = pKx[6][ci];
    float* pot = out + base + (size_t)tg * CC;

    #pragma unroll
    for (int m = 0; m < NPAIR; ++m) {
        const unsigned int u = xp[m];
        const float xv0 = __uint_as_float(u << 16);          // low bf16 = v0
        const float xv1 = __uint_as_float(u & 0xffff0000u);  // high bf16 = v1
        #pragma unroll
        for (int j = 0; j < 2; ++j) {
            const float xv = (j == 0) ? xv0 : xv1;
            const float z = fmaf(xv, a, bz);
            // binary bin search over interior knots kx1..kx7
            const bool  c4 = z >= kx4;
            const float mB = c4 ? kx6 : kx2;
            const bool  cB = z >= mB;
            const float nLo = c4 ? kx5 : kx1;
            const float nHi = c4 ? kx7 : kx3;
            const float mC = cB ? nHi : nLo;
            const bool  cC = z >= mC;
            const int off = (c4 ? 4*CT : 0) + (cB ? 2*CT : 0) + (cC ? CT : 0) + ci;

            const float2 Z = ((const float2*)bZ)[off];
            const float2 Y = ((const float2*)bY)[off];
            const float2 D = ((const float2*)bD)[off];

            const float zeta = fmaf(z, Z.y, Z.x);
            const float uu   = fmaf(-zeta, zeta, zeta);      // zeta*(1-zeta)
            const float s    = Y.y * Z.y;                    // h * invw
            const float R    = fmaf(-2.f, s, D.y);           // d0+d1-2s
            const float den  = fmaf(R, uu, s);
            const float inner= fmaf(s * zeta, zeta, D.x * uu);
            const float res  = fmaf(Y.y * inner,
                                    __builtin_amdgcn_rcpf(fmaxf(den, 1e-8f)), Y.x);
            const float o = (fabsf(z) > BOUNDF) ? z : res;
            __builtin_nontemporal_store(o, &pot[(size_t)(2*m + j) * (NTG * CC)]);
        }
    }
}

extern "C" void kernel_launch(void* const* d_in, const int* in_sizes, int n_in,
                              void* d_out, int out_size, void* d_ws, size_t ws_size,
                              hipStream_t stream) {
    const float* x  = (const float*)d_in[0];
    const float* W1 = (const float*)d_in[1];
    const float* b1 = (const float*)d_in[2];
    const float* W2 = (const float*)d_in[3];
    const float* b2 = (const float*)d_in[4];
    float* out = (float*)d_out;

    k_fused<<<dim3(CC / CT, NB), dim3(512), 0, stream>>>(x, W1, b1, W2, b2, out);
}

// Round 16
// 120.218 us; speedup vs baseline: 1.0444x; 1.0444x over previous
//
#include <hip/hip_runtime.h>
#include <math.h>

#define KNOTS 8
#define HIDN 32
#define TT 4096
#define CC 512
#define NB 32
#define BOUNDF 5.0f
#define CT 32            // channels per block
#define NTG 64           // t-rows per pass (tg = 0..63)
#define NLD 64           // f32x4 loads per thread: t = tg + 64k, k=0..63 (FULL T)
#define NPAIR 128        // bf16 pairs held in regs (4 ch x 64 t / 2)
#define TPAD 9           // padded inner dim for bin tables (bank spread)

typedef float f32x4 __attribute__((ext_vector_type(4)));

// One block = one (batch, 32-channel) slice, 512 threads = 8 c-quad lanes x 64 t-rows.
// R15 bugfix: NLD=64 covers all of T (R15's 16 left 3/4 unprocessed).
// vs R10 (121.2us): identical hold size (128 pairs, unavoidable), but ALL global
// traffic is dwordx4 -- 4x bytes-in-flight per outstanding load at the same
// 2-waves/SIMD occupancy (P1 latency fix), 128B/row NT stores (P2).
// Bin tables [4][KNOTS][9] padded: bank = 2*(9*idx+cc)%32 spreads over idx
// (R11's [16] layout made bank independent of idx -> 10.5M conflicts).
__global__ __launch_bounds__(512, 2)
void k_fused(const float* __restrict__ x, const float* __restrict__ W1,
             const float* __restrict__ b1, const float* __restrict__ W2,
             const float* __restrict__ b2, float* __restrict__ out)
{
    const int bb = blockIdx.y;               // 0..31
    const int c0 = blockIdx.x * CT;          // 0,32,...,480
    const int lc = threadIdx.x & 7;          // c-quad lane: ch 4lc..4lc+3
    const int tg = threadIdx.x >> 3;         // 0..63 t-row

    __shared__ float red[NTG][4][CT];        // 32 KB partial moments
    __shared__ float mom[4][CT];
    __shared__ float pA[CT], pB[CT];
    __shared__ float pKx[7][CT];
    __shared__ float2 bZ4[4][KNOTS][TPAD];   // (-kxl*invw, invw)
    __shared__ float2 bY4[4][KNOTS][TPAD];   // (kyl, h)
    __shared__ float2 bD4[4][KNOTS][TPAD];   // (d0, d0+d1)

    const size_t base = (size_t)bb * TT * CC + c0 + 4 * lc + (size_t)tg * CC;
    const f32x4* pxt = (const f32x4*)(x + base);

    // ---- Phase 1: read once (dwordx4), exact per-channel moments, bf16 hold ----
    unsigned int xp[NPAIR];
    float s1[4] = {0,0,0,0}, s2[4] = {0,0,0,0}, s3[4] = {0,0,0,0}, s4[4] = {0,0,0,0};
    #pragma unroll
    for (int k = 0; k < NLD; ++k) {
        const f32x4 v = pxt[(size_t)k * (NTG * CC / 4)];   // t = tg + 64k
        #pragma unroll
        for (int q = 0; q < 4; ++q) {
            const float vv = v[q];
            const float v2 = vv * vv;
            s1[q] += vv;
            s2[q] = fmaf(vv, vv, s2[q]);
            s3[q] = fmaf(v2, vv, s3[q]);
            s4[q] = fmaf(v2, v2, s4[q]);
        }
        unsigned int pk0, pk1;
        asm("v_cvt_pk_bf16_f32 %0, %1, %2" : "=v"(pk0) : "v"(v[0]), "v"(v[1]));
        asm("v_cvt_pk_bf16_f32 %0, %1, %2" : "=v"(pk1) : "v"(v[2]), "v"(v[3]));
        xp[2*k]   = pk0;
        xp[2*k+1] = pk1;
    }
    #pragma unroll
    for (int q = 0; q < 4; ++q) {
        red[tg][0][4*lc+q] = s1[q];
        red[tg][1][4*lc+q] = s2[q];
        red[tg][2][4*lc+q] = s3[q];
        red[tg][3][4*lc+q] = s4[q];
    }
    __syncthreads();

    if (threadIdx.x < 4 * CT) {
        const int m = threadIdx.x >> 5, c = threadIdx.x & (CT - 1);
        float acc = 0.f;
        #pragma unroll
        for (int g = 0; g < NTG; ++g) acc += red[g][m][c];
        mom[m][c] = acc;
    }
    __syncthreads();

    // ---- Finalize: one lane per channel ----
    if (threadIdx.x < CT) {
        const int c = threadIdx.x;
        const float n  = (float)TT;
        const float t1 = mom[0][c], t2 = mom[1][c], t3 = mom[2][c], t4 = mom[3][c];
        const float mu  = t1 / n;
        const float ex2 = t2 / n, ex3 = t3 / n, ex4 = t4 / n;
        float var = (t2 - n * mu * mu) / (n - 1.f);
        var = fmaxf(var, 0.f);
        const float sig  = fmaxf(sqrtf(var), 1e-4f);
        const float inv  = 1.f / sig;
        const float mu2  = mu * mu;
        const float ez3  = ex3 - 3.f * mu * ex2 + 2.f * mu * mu2;
        const float ez4  = ex4 - 4.f * mu * ex3 + 6.f * mu2 * ex2 - 3.f * mu2 * mu2;
        const float inv2 = inv * inv;
        const float skew  = ez3 * inv2 * inv;
        const float ekurt = ez4 * inv2 * inv2 - 3.f;

        float hid[HIDN];
        #pragma unroll
        for (int h = 0; h < HIDN; ++h) {
            float v = fmaf(W1[2*h], skew, fmaf(W1[2*h+1], ekurt, b1[h]));
            hid[h] = fmaxf(v, 0.f);
        }

        float e[KNOTS], kxr[KNOTS+1], kyr[KNOTS+1], dr[KNOTS+1];
        {   // widths -> kx
            float mx = -1e30f;
            #pragma unroll
            for (int o = 0; o < KNOTS; ++o) {
                float acc = b2[o];
                #pragma unroll
                for (int h = 0; h < HIDN; ++h) acc = fmaf(W2[o*HIDN + h], hid[h], acc);
                e[o] = acc; mx = fmaxf(mx, acc);
            }
            float sum = 0.f;
            #pragma unroll
            for (int o = 0; o < KNOTS; ++o) { e[o] = expf(e[o] - mx); sum += e[o]; }
            const float scale = (2.f * BOUNDF) / sum;
            float cum = -BOUNDF; kxr[0] = -BOUNDF;
            #pragma unroll
            for (int o = 0; o < KNOTS; ++o) { cum = fmaf(e[o], scale, cum); kxr[o+1] = cum; }
        }
        {   // heights -> ky
            float mx = -1e30f;
            #pragma unroll
            for (int o = 0; o < KNOTS; ++o) {
                float acc = b2[KNOTS + o];
                #pragma unroll
                for (int h = 0; h < HIDN; ++h) acc = fmaf(W2[(KNOTS+o)*HIDN + h], hid[h], acc);
                e[o] = acc; mx = fmaxf(mx, acc);
            }
            float sum = 0.f;
            #pragma unroll
            for (int o = 0; o < KNOTS; ++o) { e[o] = expf(e[o] - mx); sum += e[o]; }
            const float scale = (2.f * BOUNDF) / sum;
            float cum = -BOUNDF; kyr[0] = -BOUNDF;
            #pragma unroll
            for (int o = 0; o < KNOTS; ++o) { cum = fmaf(e[o], scale, cum); kyr[o+1] = cum; }
        }
        #pragma unroll
        for (int o = 0; o < KNOTS+1; ++o) {  // derivs = softplus + 1e-3
            float acc = b2[2*KNOTS + o];
            #pragma unroll
            for (int h = 0; h < HIDN; ++h) acc = fmaf(W2[(2*KNOTS+o)*HIDN + h], hid[h], acc);
            float sp = fmaxf(acc, 0.f) + log1pf(expf(-fabsf(acc)));
            dr[o] = sp + 1e-3f;
        }

        pA[c] = inv;
        pB[c] = -mu * inv;
        #pragma unroll
        for (int j = 1; j <= 7; ++j) pKx[j-1][c] = kxr[j];
        const int q = c & 3, cc = c >> 2;
        #pragma unroll
        for (int j = 0; j < KNOTS; ++j) {
            const float w    = kxr[j+1] - kxr[j];
            const float wm   = fmaxf(w, 1e-8f);
            const float invw = 1.f / wm;
            const float h    = kyr[j+1] - kyr[j];
            bZ4[q][j][cc] = make_float2(-kxr[j] * invw, invw);
            bY4[q][j][cc] = make_float2(kyr[j], h);
            bD4[q][j][cc] = make_float2(dr[j], dr[j] + dr[j+1]);
        }
    }
    __syncthreads();

    // ---- Phase 2: unpack regs, 4 channel chains, dwordx4 NT store ----
    float aq[4], bq[4], kx[4][7];
    #pragma unroll
    for (int q = 0; q < 4; ++q) {
        const int c = 4*lc + q;
        aq[q] = pA[c];
        bq[q] = pB[c];
        #pragma unroll
        for (int j = 0; j < 7; ++j) kx[q][j] = pKx[j][c];
    }
    f32x4* pot = (f32x4*)(out + base);

    #pragma unroll
    for (int k = 0; k < NLD; ++k) {
        const unsigned int u0 = xp[2*k], u1 = xp[2*k+1];
        float xv[4];
        xv[0] = __uint_as_float(u0 << 16);
        xv[1] = __uint_as_float(u0 & 0xffff0000u);
        xv[2] = __uint_as_float(u1 << 16);
        xv[3] = __uint_as_float(u1 & 0xffff0000u);
        f32x4 r;
        #pragma unroll
        for (int q = 0; q < 4; ++q) {
            const float z = fmaf(xv[q], aq[q], bq[q]);
            const bool  c4 = z >= kx[q][3];
            const float mB = c4 ? kx[q][5] : kx[q][1];
            const bool  cB = z >= mB;
            const float nLo = c4 ? kx[q][4] : kx[q][0];
            const float nHi = c4 ? kx[q][6] : kx[q][2];
            const float mC = cB ? nHi : nLo;
            const bool  cC = z >= mC;
            const int idx = (c4 ? 4 : 0) + (cB ? 2 : 0) + (cC ? 1 : 0);

            const float2 Z = bZ4[q][idx][lc];
            const float2 Y = bY4[q][idx][lc];
            const float2 D = bD4[q][idx][lc];

            const float zeta = fmaf(z, Z.y, Z.x);
            const float uu   = fmaf(-zeta, zeta, zeta);      // zeta*(1-zeta)
            const float s    = Y.y * Z.y;                    // h * invw
            const float R    = fmaf(-2.f, s, D.y);           // d0+d1-2s
            const float den  = fmaf(R, uu, s);
            const float inner= fmaf(s * zeta, zeta, D.x * uu);
            const float res  = fmaf(Y.y * inner,
                                    __builtin_amdgcn_rcpf(fmaxf(den, 1e-8f)), Y.x);
            r[q] = (fabsf(z) > BOUNDF) ? z : res;
        }
        __builtin_nontemporal_store(r, &pot[(size_t)k * (NTG * CC / 4)]);
    }
}

extern "C" void kernel_launch(void* const* d_in, const int* in_sizes, int n_in,
                              void* d_out, int out_size, void* d_ws, size_t ws_size,
                              hipStream_t stream) {
    const float* x  = (const float*)d_in[0];
    const float* W1 = (const float*)d_in[1];
    const float* b1 = (const float*)d_in[2];
    const float* W2 = (const float*)d_in[3];
    const float* b2 = (const float*)d_in[4];
    float* out = (float*)d_out;

    k_fused<<<dim3(CC / CT, NB), dim3(512), 0, stream>>>(x, W1, b1, W2, b2, out);
}